// Round 4
// baseline (123.769 us; speedup 1.0000x reference)
//
#include <hip/hip_runtime.h>

// PatchMask fused single-kernel:
//   out[b,c,t] = x[b,c,t] * (bit(c*NP + t/PATCH) ? 0 : 1)
// B=128, C=128, T=5000, PATCH=25, NP=200, UNITS=25600, NMASK=2560
// Per-block LDS bitmask (3.2 KB) built from idx, then nontemporal stream.

#define PM_B 128
#define PM_C 128
#define PM_T 5000
#define PM_PATCH 25
#define PM_NP 200                      // PM_T / PM_PATCH
#define PM_UNITS (PM_C * PM_NP)        // 25600
#define PM_NMASK 2560
#define PM_F4_PER_ROW (PM_T / 4)       // 1250
#define PM_F4_TOTAL (PM_B * PM_C * PM_F4_PER_ROW)  // 20,480,000
#define PM_MWORDS (PM_UNITS / 32)      // 800

typedef float f32x4 __attribute__((ext_vector_type(4)));

__device__ __forceinline__ void pm_process(
    unsigned i, const f32x4* __restrict__ x, f32x4* __restrict__ out,
    const unsigned* mbits)
{
    const unsigned row = i / PM_F4_PER_ROW;            // b*C + c (magic-mul)
    const unsigned t0  = (i - row * PM_F4_PER_ROW) * 4u;
    const unsigned cbase = (row & (PM_C - 1)) * PM_NP;

    f32x4 v = __builtin_nontemporal_load(x + i);

    const unsigned p0 = t0 / PM_PATCH;
    const unsigned p3 = (t0 + 3u) / PM_PATCH;
    const unsigned u0 = cbase + p0;
    const float m0 = ((mbits[u0 >> 5] >> (u0 & 31u)) & 1u) ? 0.0f : 1.0f;
    if (p0 == p3) {
        v *= m0;
    } else {
        const unsigned u3 = cbase + p3;
        const float m3 = ((mbits[u3 >> 5] >> (u3 & 31u)) & 1u) ? 0.0f : 1.0f;
        const unsigned boundary = p3 * PM_PATCH;       // first t in patch p3
        v.x *= (t0 + 0u < boundary) ? m0 : m3;
        v.y *= (t0 + 1u < boundary) ? m0 : m3;
        v.z *= (t0 + 2u < boundary) ? m0 : m3;
        v.w *= (t0 + 3u < boundary) ? m0 : m3;
    }

    __builtin_nontemporal_store(v, out + i);
}

__global__ __launch_bounds__(256) void pm_fused(
    const f32x4* __restrict__ x,
    const int* __restrict__ idx,
    f32x4* __restrict__ out)
{
    __shared__ unsigned mbits[PM_MWORDS];              // 3.2 KB

    // Build bitmask: zero, scatter-or, barrier.
    for (unsigned w = threadIdx.x; w < PM_MWORDS; w += 256u)
        mbits[w] = 0u;
    __syncthreads();
    for (unsigned j = threadIdx.x; j < PM_NMASK; j += 256u) {
        const unsigned u = (unsigned)idx[j];
        atomicOr(&mbits[u >> 5], 1u << (u & 31u));
    }
    __syncthreads();

    // Streaming apply, unroll x2 for MLP.
    unsigned i = blockIdx.x * 256u + threadIdx.x;
    const unsigned stride = gridDim.x * 256u;
    for (; i + stride < PM_F4_TOTAL; i += 2u * stride) {
        pm_process(i,          x, out, mbits);
        pm_process(i + stride, x, out, mbits);
    }
    if (i < PM_F4_TOTAL)
        pm_process(i, x, out, mbits);
}

extern "C" void kernel_launch(void* const* d_in, const int* in_sizes, int n_in,
                              void* d_out, int out_size, void* d_ws, size_t ws_size,
                              hipStream_t stream) {
    const float* x   = (const float*)d_in[0];
    const int*   idx = (const int*)d_in[1];
    float*       out = (float*)d_out;

    // 2048 blocks x 256 threads = 8 blocks/CU = 32 waves/CU (max occupancy)
    pm_fused<<<2048, 256, 0, stream>>>(
        (const f32x4*)x, idx, (f32x4*)out);
}